// Round 1
// baseline (21106.822 us; speedup 1.0000x reference)
//
#include <hip/hip_runtime.h>
#include <hip/hip_bf16.h>

#define VOCAB 78
#define EMBED 8
#define HID 256
#define BATCH 512
#define SEQ 512
#define G4H 1024  // 4*HID

typedef short bf16x8 __attribute__((ext_vector_type(8)));
typedef float f32x4 __attribute__((ext_vector_type(4)));

// ---- workspace layout (bytes) ----
#define OFF_WHH0 0
#define OFF_WIH1 (512*1024)
#define OFF_WHH1 (1024*1024)
#define OFF_XG0  (1536*1024)            // 78*1024*4 = 319488
#define OFF_B1   (OFF_XG0 + 320*1024)
#define OFF_XT   (OFF_B1 + 4096)        // 512*512*4 = 1 MB
#define WS_NEED  (OFF_XT + SEQ*BATCH*4) // ~2.9 MB

__device__ __forceinline__ float sigm(float x){ return 1.f/(1.f + __expf(-x)); }
__device__ __forceinline__ float tanh_f(float x){
  // overflow-safe tanh via exp of negative argument only
  float e = __expf(-2.f * fabsf(x));
  float r = (1.f - e) / (1.f + e);
  return copysignf(r, x);
}
__device__ __forceinline__ unsigned short f2b(float x){
  // round-to-nearest-even fp32 -> bf16 (values are finite; no NaN path needed)
  unsigned u = __float_as_uint(x);
  unsigned r = (u + 0x7FFFu + ((u >> 16) & 1u)) >> 16;
  return (unsigned short)r;
}

// ---------------- prep: weight bf16 conversion, xg0 table, x transpose, fused bias1
__global__ void prep(const int* __restrict__ x, const float* __restrict__ E,
                     const float* __restrict__ Wih0, const float* __restrict__ Whh0,
                     const float* __restrict__ bih0, const float* __restrict__ bhh0,
                     const float* __restrict__ Wih1, const float* __restrict__ Whh1,
                     const float* __restrict__ bih1, const float* __restrict__ bhh1,
                     unsigned char* __restrict__ ws)
{
  unsigned short* Whh0b = (unsigned short*)(ws + OFF_WHH0);
  unsigned short* Wih1b = (unsigned short*)(ws + OFF_WIH1);
  unsigned short* Whh1b = (unsigned short*)(ws + OFF_WHH1);
  float* xg0 = (float*)(ws + OFF_XG0);
  float* b1  = (float*)(ws + OFF_B1);
  int*   xT  = (int*)(ws + OFF_XT);

  long id = (long)blockIdx.x * 256 + threadIdx.x;
  const long NW = 1024L * 256;
  if (id < NW) { Whh0b[id] = f2b(Whh0[id]); return; }
  id -= NW;
  if (id < NW) { Wih1b[id] = f2b(Wih1[id]); return; }
  id -= NW;
  if (id < NW) { Whh1b[id] = f2b(Whh1[id]); return; }
  id -= NW;
  if (id < (long)VOCAB*G4H) {
    int v = (int)(id / G4H), row = (int)(id % G4H);
    float s = bih0[row] + bhh0[row];
    if (v != 0) {                       // padding_idx=0 -> zero embedding
      #pragma unroll
      for (int e = 0; e < EMBED; e++) s += E[v*EMBED + e] * Wih0[row*EMBED + e];
    }
    xg0[id] = s; return;
  }
  id -= (long)VOCAB*G4H;
  if (id < (long)SEQ*BATCH) {
    int t = (int)(id / BATCH), b = (int)(id % BATCH);
    xT[t*BATCH + b] = x[b*SEQ + t]; return;
  }
  id -= (long)SEQ*BATCH;
  if (id < G4H) { b1[id] = bih1[id] + bhh1[id]; }
}

// ---------------- fused 2-layer LSTM + FC. One WG per 16 batch rows, no inter-WG sync.
// 1024 threads = 16 waves; wave w owns hidden slice j in [16w,16w+16) for all 4 gates.
// MFMA 16x16x32: A rows = batch (lane&15), B cols = gate rows (lane&15);
// C/D: col = lane&15 (gate), row = (lane>>4)*4 + reg (batch)  [m89-verified mapping]
__global__ __launch_bounds__(1024, 1) void lstm_all(const unsigned char* __restrict__ ws,
    const float* __restrict__ Wfc, const float* __restrict__ bfc, float* __restrict__ out)
{
  const unsigned short* Whh0b = (const unsigned short*)(ws + OFF_WHH0);
  const unsigned short* Wih1b = (const unsigned short*)(ws + OFF_WIH1);
  const unsigned short* Whh1b = (const unsigned short*)(ws + OFF_WHH1);
  const float* xg0 = (const float*)(ws + OFF_XG0);
  const float* b1  = (const float*)(ws + OFF_B1);
  const int*   xT  = (const int*)(ws + OFF_XT);

  __shared__ __align__(16) unsigned short h0s[2][16][264]; // +8 bf16 row pad: bank spread
  __shared__ __align__(16) unsigned short h1s[2][16][264];
  __shared__ __align__(16) float h1f[16][256];             // f32 last-step h for FC

  const int tid = threadIdx.x;
  const int w  = tid >> 6;          // wave 0..15
  const int l  = tid & 63;
  const int lc = l & 15, lq = l >> 4;
  const int b0 = blockIdx.x * 16;
  const int jw = 16*w + lc;         // hidden index (output col) this lane covers

  for (int i = tid; i < 2*16*264; i += 1024) {
    ((unsigned short*)h0s)[i] = 0;
    ((unsigned short*)h1s)[i] = 0;
  }
  __syncthreads();

  float c0[4] = {0,0,0,0}, c1[4] = {0,0,0,0};
  float bias1v[4];
  #pragma unroll
  for (int g = 0; g < 4; g++) bias1v[g] = b1[g*HID + jw];

  // per-lane weight fragment base pointers (4 gate rows each matrix)
  const unsigned short *w0p[4], *w1p[4], *w2p[4];
  #pragma unroll
  for (int g = 0; g < 4; g++) {
    int row = g*HID + jw;
    w0p[g] = Whh0b + (long)row*HID + lq*8;
    w1p[g] = Wih1b + (long)row*HID + lq*8;
    w2p[g] = Whh1b + (long)row*HID + lq*8;
  }

  int p = 0;
  #pragma unroll 1
  for (int t = 0; t < SEQ; ++t) {
    // token-table gather for this step (independent of MFMAs -> overlaps them)
    float xg[4][4];
    #pragma unroll
    for (int r = 0; r < 4; r++) {
      int tok = xT[t*BATCH + b0 + lq*4 + r];
      const float* tr = xg0 + (long)tok*G4H + jw;
      #pragma unroll
      for (int g = 0; g < 4; g++) xg[g][r] = tr[g*HID];
    }

    // ---- layer 0: gates = xg0[tok] + h0 @ Whh0^T
    f32x4 acc[4] = {{0,0,0,0},{0,0,0,0},{0,0,0,0},{0,0,0,0}};
    #pragma unroll
    for (int kt = 0; kt < 8; kt++) {
      bf16x8 a = *(const bf16x8*)((const void*)&h0s[p][lc][kt*32 + lq*8]);
      #pragma unroll
      for (int g = 0; g < 4; g++) {
        bf16x8 b = *(const bf16x8*)((const void*)(w0p[g] + kt*32));
        acc[g] = __builtin_amdgcn_mfma_f32_16x16x32_bf16(a, b, acc[g], 0, 0, 0);
      }
    }
    #pragma unroll
    for (int r = 0; r < 4; r++) {
      float gi = sigm(acc[0][r] + xg[0][r]);
      float gf = sigm(acc[1][r] + xg[1][r]);
      float gg = tanh_f(acc[2][r] + xg[2][r]);
      float go = sigm(acc[3][r] + xg[3][r]);
      float c = gf*c0[r] + gi*gg;
      c0[r] = c;
      float h = go * tanh_f(c);
      h0s[p^1][lq*4 + r][jw] = f2b(h);
    }
    __syncthreads();

    // ---- layer 1: gates = bias1 + h0_t @ Wih1^T + h1 @ Whh1^T
    f32x4 acc2[4];
    #pragma unroll
    for (int g = 0; g < 4; g++) { f32x4 v = {bias1v[g], bias1v[g], bias1v[g], bias1v[g]}; acc2[g] = v; }
    #pragma unroll
    for (int kt = 0; kt < 8; kt++) {
      bf16x8 a1 = *(const bf16x8*)((const void*)&h0s[p^1][lc][kt*32 + lq*8]);
      #pragma unroll
      for (int g = 0; g < 4; g++) {
        bf16x8 b = *(const bf16x8*)((const void*)(w1p[g] + kt*32));
        acc2[g] = __builtin_amdgcn_mfma_f32_16x16x32_bf16(a1, b, acc2[g], 0, 0, 0);
      }
      bf16x8 a2 = *(const bf16x8*)((const void*)&h1s[p][lc][kt*32 + lq*8]);
      #pragma unroll
      for (int g = 0; g < 4; g++) {
        bf16x8 b = *(const bf16x8*)((const void*)(w2p[g] + kt*32));
        acc2[g] = __builtin_amdgcn_mfma_f32_16x16x32_bf16(a2, b, acc2[g], 0, 0, 0);
      }
    }
    #pragma unroll
    for (int r = 0; r < 4; r++) {
      float gi = sigm(acc2[0][r]);
      float gf = sigm(acc2[1][r]);
      float gg = tanh_f(acc2[2][r]);
      float go = sigm(acc2[3][r]);
      float c = gf*c1[r] + gi*gg;
      c1[r] = c;
      float h = go * tanh_f(c);
      h1s[p^1][lq*4 + r][jw] = f2b(h);
      if (t == SEQ-1) h1f[lq*4 + r][jw] = h;   // keep f32 for FC
    }
    __syncthreads();
    p ^= 1;
  }

  // ---- FC on last h1: out[16][78] = h1 @ Wfc^T + bfc
  for (int pair = tid; pair < 16*VOCAB; pair += 1024) {
    int bb = pair / VOCAB, v = pair % VOCAB;
    float s = bfc[v];
    const float* wr = Wfc + v*HID;
    #pragma unroll 4
    for (int k = 0; k < HID; k++) s += h1f[bb][k] * wr[k];
    out[(b0 + bb)*VOCAB + v] = s;
  }
}

extern "C" void kernel_launch(void* const* d_in, const int* in_sizes, int n_in,
                              void* d_out, int out_size, void* d_ws, size_t ws_size,
                              hipStream_t stream) {
  const int*   x    = (const int*)  d_in[0];
  const float* E    = (const float*)d_in[1];
  const float* Wih0 = (const float*)d_in[2];
  const float* Whh0 = (const float*)d_in[3];
  const float* bih0 = (const float*)d_in[4];
  const float* bhh0 = (const float*)d_in[5];
  const float* Wih1 = (const float*)d_in[6];
  const float* Whh1 = (const float*)d_in[7];
  const float* bih1 = (const float*)d_in[8];
  const float* bhh1 = (const float*)d_in[9];
  const float* Wfc  = (const float*)d_in[10];
  const float* bfc  = (const float*)d_in[11];
  unsigned char* ws = (unsigned char*)d_ws;

  // 3*262144 + 79872 + 262144 + 1024 = 1,129,472 work items = 4412 * 256 exactly
  prep<<<4412, 256, 0, stream>>>(x, E, Wih0, Whh0, bih0, bhh0, Wih1, Whh1, bih1, bhh1, ws);
  lstm_all<<<BATCH/16, 1024, 0, stream>>>(ws, Wfc, bfc, (float*)d_out);
}

// Round 2
// 9223.265 us; speedup vs baseline: 2.2884x; 2.2884x over previous
//
#include <hip/hip_runtime.h>
#include <hip/hip_bf16.h>

#define VOCAB 78
#define EMBED 8
#define HID 256
#define BATCH 512
#define SEQ 512
#define G4H 1024

#define GB 8    // batch groups
#define GH 16   // hidden groups -> 128 WGs, 1 per CU (LDS-bound)
#define BS 64   // batch rows per WG (4 waves x 16-row M-tiles)
#define HS 16   // hidden cols per WG (64 gate rows/matrix in LDS)

typedef short bf16x8 __attribute__((ext_vector_type(8)));
typedef float f32x4 __attribute__((ext_vector_type(4)));
typedef unsigned long long u64;

// ---- workspace layout (bytes) ----
#define OFF_WHH0 0                         // 512KB bf16 [1024][256]
#define OFF_WIH1 (512*1024)                // 512KB
#define OFF_WHH1 (1024*1024)               // 512KB
#define OFF_XG0  (1536*1024)               // 78*1024*4 = 319488
#define OFF_B1   (OFF_XG0 + 320*1024)      // 4KB
#define OFF_XT   (OFF_B1 + 4096)           // 1MB int [512][512]
#define OFF_H0   (OFF_XT + 1024*1024)      // 2 x [512][256] bf16 = 512KB
#define OFF_H1   (OFF_H0 + 512*1024)       // 512KB
#define OFF_H1F  (OFF_H1 + 512*1024)       // [512][256] f32 = 512KB
#define OFF_CNT  (OFF_H1F + 512*1024)      // 1KB counters
#define WS_NEED  (OFF_CNT + 1024)

__device__ __forceinline__ float sigm(float x){ return 1.f/(1.f + __expf(-x)); }
__device__ __forceinline__ float tanh_f(float x){
  float e = __expf(-2.f * fabsf(x));
  float r = (1.f - e) / (1.f + e);
  return copysignf(r, x);
}
__device__ __forceinline__ unsigned short f2b(float x){
  unsigned u = __float_as_uint(x);
  unsigned r = (u + 0x7FFFu + ((u >> 16) & 1u)) >> 16;
  return (unsigned short)r;
}

// ---------------- prep: bf16 weights, xg0 token table, x transpose, bias1, zero h/counters
__global__ void prep(const int* __restrict__ x, const float* __restrict__ E,
                     const float* __restrict__ Wih0, const float* __restrict__ Whh0,
                     const float* __restrict__ bih0, const float* __restrict__ bhh0,
                     const float* __restrict__ Wih1, const float* __restrict__ Whh1,
                     const float* __restrict__ bih1, const float* __restrict__ bhh1,
                     unsigned char* __restrict__ ws)
{
  unsigned short* Whh0b = (unsigned short*)(ws + OFF_WHH0);
  unsigned short* Wih1b = (unsigned short*)(ws + OFF_WIH1);
  unsigned short* Whh1b = (unsigned short*)(ws + OFF_WHH1);
  float* xg0 = (float*)(ws + OFF_XG0);
  float* b1  = (float*)(ws + OFF_B1);
  int*   xT  = (int*)(ws + OFF_XT);

  long id = (long)blockIdx.x * 256 + threadIdx.x;
  const long NW = 1024L * 256;
  if (id < NW) { Whh0b[id] = f2b(Whh0[id]); return; }
  id -= NW;
  if (id < NW) { Wih1b[id] = f2b(Wih1[id]); return; }
  id -= NW;
  if (id < NW) { Whh1b[id] = f2b(Whh1[id]); return; }
  id -= NW;
  if (id < (long)VOCAB*G4H) {
    int v = (int)(id / G4H), row = (int)(id % G4H);
    float s = bih0[row] + bhh0[row];
    if (v != 0) {                       // padding_idx=0 -> zero embedding
      #pragma unroll
      for (int e = 0; e < EMBED; e++) s += E[v*EMBED + e] * Wih0[row*EMBED + e];
    }
    xg0[id] = s; return;
  }
  id -= (long)VOCAB*G4H;
  if (id < (long)SEQ*BATCH) {
    int t = (int)(id / BATCH), b = (int)(id % BATCH);
    xT[t*BATCH + b] = x[b*SEQ + t]; return;
  }
  id -= (long)SEQ*BATCH;
  if (id < G4H) { b1[id] = bih1[id] + bhh1[id]; return; }
  id -= G4H;
  if (id < 262144) { ((unsigned*)(ws + OFF_H0))[id] = 0u; return; }  // h0+h1 both parities
  id -= 262144;
  if (id < 256) { ((unsigned*)(ws + OFF_CNT))[id] = 0u; }
}

// ---------------- weight-stationary synchronized LSTM
// grid=128: gb=bid&7 (batch group of 16 WGs), gh=bid>>3 (hidden slice).
// Weights (3 x 64 gate-rows x 256) live in LDS, XOR-swizzled for ds_read_b128.
// Per step: L0 -> write h0 slice -> signal A -> wait B(t-1) & A(t) -> L1 -> write h1 -> signal B.
__global__ __launch_bounds__(256, 1) void lstm_sync(unsigned char* __restrict__ ws)
{
  const unsigned short* Wg = (const unsigned short*)(ws + OFF_WHH0); // 3 matrices contiguous
  const float* xg0 = (const float*)(ws + OFF_XG0);
  const float* b1  = (const float*)(ws + OFF_B1);
  const int*   xT  = (const int*)(ws + OFF_XT);
  unsigned short* h0g = (unsigned short*)(ws + OFF_H0);  // [2][512][256]
  unsigned short* h1g = (unsigned short*)(ws + OFF_H1);
  float* h1f = (float*)(ws + OFF_H1F);
  unsigned* cntA = (unsigned*)(ws + OFF_CNT);            // [gb*16]
  unsigned* cntB = (unsigned*)(ws + OFF_CNT + 512);

  __shared__ __align__(16) unsigned char smem[3*32768 + 64*40];
  unsigned char* wlds = smem;
  unsigned char* hb   = smem + 3*32768;   // [64 rows][40B] bf16 bounce (stride 40: bank-spread)

  const int tid = threadIdx.x;
  const int m = tid >> 6, l = tid & 63, lc = l & 15, lq = l >> 4;
  const int gb = blockIdx.x & 7, gh = blockIdx.x >> 3;
  const int B0 = gb * BS, J = gh * HS;
  const int brow0 = B0 + m*16;

  // --- stage weight slices into LDS (once). cw = g*16 + c, global row g*256+J+c.
  for (int idx = tid; idx < 3*64*32; idx += 256) {
    int mat = idx >> 11;
    int rem = idx & 2047;
    int cw  = rem >> 5;
    int c16 = rem & 31;
    int g = cw >> 4, r16 = cw & 15;
    int grow = g*256 + J + r16;
    bf16x8 v = *(const bf16x8*)(Wg + (size_t)mat*262144 + (size_t)grow*256 + c16*8);
    *(bf16x8*)(wlds + mat*32768 + cw*512 + ((c16*16) ^ ((cw&7)<<4))) = v;
  }

  float bias1v[4];
  #pragma unroll
  for (int g = 0; g < 4; g++) bias1v[g] = b1[g*256 + J + lc];

  // per-lane weight LDS base offsets (B-frag: col=lc within gate tile g)
  int wb[3][4];
  const int swz = (lc & 7) << 4;
  #pragma unroll
  for (int g = 0; g < 4; g++) {
    int cw = g*16 + lc;
    wb[0][g] = 0*32768 + cw*512;
    wb[1][g] = 1*32768 + cw*512;
    wb[2][g] = 2*32768 + cw*512;
  }
  __syncthreads();

  float c0[4] = {0,0,0,0}, c1[4] = {0,0,0,0};

#define MM(acc, a, mat)                                                          \
  _Pragma("unroll") for (int kt = 0; kt < 8; kt++) {                             \
    _Pragma("unroll") for (int g = 0; g < 4; g++) {                              \
      bf16x8 bfr = *(const bf16x8*)(wlds + wb[mat][g] + ((kt*64 + lq*16) ^ swz));\
      acc[g] = __builtin_amdgcn_mfma_f32_16x16x32_bf16(a[kt], bfr, acc[g], 0,0,0);\
    } }

  #pragma unroll 1
  for (int t = 0; t < SEQ; ++t) {
    const int par = t & 1, parp = par ^ 1;

    // token-table gather (overlaps frag loads/MFMA)
    float xg[4][4];
    #pragma unroll
    for (int r = 0; r < 4; r++) {
      int tok = xT[t*BATCH + brow0 + lq*4 + r];
      const float* tr = xg0 + (size_t)tok*G4H + J + lc;
      #pragma unroll
      for (int g = 0; g < 4; g++) xg[g][r] = tr[g*256];
    }

    // ---- layer 0: acc0 = h0[t-1] @ Whh0^T (slice)
    bf16x8 a0[8];
    { const unsigned short* hp = h0g + (size_t)parp*131072 + (size_t)(brow0+lc)*256 + lq*8;
      #pragma unroll
      for (int kt = 0; kt < 8; kt++) a0[kt] = *(const bf16x8*)(hp + kt*32); }
    f32x4 acc0[4] = {{0,0,0,0},{0,0,0,0},{0,0,0,0},{0,0,0,0}};
    MM(acc0, a0, 0);

    #pragma unroll
    for (int r = 0; r < 4; r++) {
      float gi = sigm (acc0[0][r] + xg[0][r]);
      float gf = sigm (acc0[1][r] + xg[1][r]);
      float gg = tanh_f(acc0[2][r] + xg[2][r]);
      float go = sigm (acc0[3][r] + xg[3][r]);
      float c = gf*c0[r] + gi*gg;  c0[r] = c;
      float h = go * tanh_f(c);
      *(unsigned short*)(hb + (m*16 + lq*4 + r)*40 + lc*2) = f2b(h);
    }
    __syncthreads();
    // packed 8B agent-coherent store of our [64,16] h0 slice
    { u64 pv = *(const u64*)(hb + (tid>>2)*40 + (tid&3)*8);
      u64* dp = (u64*)(h0g + (size_t)par*131072 + (size_t)(B0 + (tid>>2))*256 + J + (tid&3)*4);
      __hip_atomic_store(dp, pv, __ATOMIC_RELAXED, __HIP_MEMORY_SCOPE_AGENT); }
    __builtin_amdgcn_fence(__ATOMIC_RELEASE, "agent");
    __syncthreads();
    if (tid == 0)
      __hip_atomic_fetch_add(&cntA[gb*16], 1u, __ATOMIC_RELAXED, __HIP_MEMORY_SCOPE_AGENT);

    // ---- wait h1[t-1] complete (B(t-1)) and h0[t] complete (A(t)); single acquire
    if (tid == 0) {
      unsigned tb = 16u * (unsigned)t;
      while (__hip_atomic_load(&cntB[gb*16], __ATOMIC_RELAXED, __HIP_MEMORY_SCOPE_AGENT) < tb)
        __builtin_amdgcn_s_sleep(2);
      unsigned ta = 16u * (unsigned)(t + 1);
      while (__hip_atomic_load(&cntA[gb*16], __ATOMIC_RELAXED, __HIP_MEMORY_SCOPE_AGENT) < ta)
        __builtin_amdgcn_s_sleep(2);
    }
    __syncthreads();
    __builtin_amdgcn_fence(__ATOMIC_ACQUIRE, "agent");

    // ---- layer 1: acc2 = bias1 + h1[t-1] @ Whh1^T + h0[t] @ Wih1^T  (slices)
    f32x4 acc2[4];
    #pragma unroll
    for (int g = 0; g < 4; g++) { f32x4 v = {bias1v[g],bias1v[g],bias1v[g],bias1v[g]}; acc2[g] = v; }
    bf16x8 a1[8];
    { const unsigned short* hp = h1g + (size_t)parp*131072 + (size_t)(brow0+lc)*256 + lq*8;
      #pragma unroll
      for (int kt = 0; kt < 8; kt++) a1[kt] = *(const bf16x8*)(hp + kt*32); }
    MM(acc2, a1, 2);
    bf16x8 a2[8];
    { const unsigned short* hp = h0g + (size_t)par*131072 + (size_t)(brow0+lc)*256 + lq*8;
      #pragma unroll
      for (int kt = 0; kt < 8; kt++) a2[kt] = *(const bf16x8*)(hp + kt*32); }
    MM(acc2, a2, 1);

    #pragma unroll
    for (int r = 0; r < 4; r++) {
      float gi = sigm (acc2[0][r]);
      float gf = sigm (acc2[1][r]);
      float gg = tanh_f(acc2[2][r]);
      float go = sigm (acc2[3][r]);
      float c = gf*c1[r] + gi*gg;  c1[r] = c;
      float h = go * tanh_f(c);
      *(unsigned short*)(hb + (m*16 + lq*4 + r)*40 + lc*2) = f2b(h);
      if (t == SEQ-1) h1f[(size_t)(brow0 + lq*4 + r)*256 + J + lc] = h;  // f32 for FC
    }
    __syncthreads();
    { u64 pv = *(const u64*)(hb + (tid>>2)*40 + (tid&3)*8);
      u64* dp = (u64*)(h1g + (size_t)par*131072 + (size_t)(B0 + (tid>>2))*256 + J + (tid&3)*4);
      __hip_atomic_store(dp, pv, __ATOMIC_RELAXED, __HIP_MEMORY_SCOPE_AGENT); }
    __builtin_amdgcn_fence(__ATOMIC_RELEASE, "agent");
    __syncthreads();
    if (tid == 0)
      __hip_atomic_fetch_add(&cntB[gb*16], 1u, __ATOMIC_RELAXED, __HIP_MEMORY_SCOPE_AGENT);
  }
#undef MM
}

// ---------------- FC: out[512][78] = h1_last @ Wfc^T + bfc  (20 MFLOP, trivial)
__global__ void fc_kernel(const unsigned char* __restrict__ ws,
                          const float* __restrict__ Wfc, const float* __restrict__ bfc,
                          float* __restrict__ out)
{
  int b = blockIdx.x, v = threadIdx.x;
  if (v >= VOCAB) return;
  const float* h = (const float*)(ws + OFF_H1F) + (size_t)b*HID;
  const float* w = Wfc + (size_t)v*HID;
  float s = bfc[v];
  #pragma unroll 4
  for (int k = 0; k < HID; k += 4)
    s += h[k]*w[k] + h[k+1]*w[k+1] + h[k+2]*w[k+2] + h[k+3]*w[k+3];
  out[(size_t)b*VOCAB + v] = s;
}

extern "C" void kernel_launch(void* const* d_in, const int* in_sizes, int n_in,
                              void* d_out, int out_size, void* d_ws, size_t ws_size,
                              hipStream_t stream) {
  const int*   x    = (const int*)  d_in[0];
  const float* E    = (const float*)d_in[1];
  const float* Wih0 = (const float*)d_in[2];
  const float* Whh0 = (const float*)d_in[3];
  const float* bih0 = (const float*)d_in[4];
  const float* bhh0 = (const float*)d_in[5];
  const float* Wih1 = (const float*)d_in[6];
  const float* Whh1 = (const float*)d_in[7];
  const float* bih1 = (const float*)d_in[8];
  const float* bhh1 = (const float*)d_in[9];
  const float* Wfc  = (const float*)d_in[10];
  const float* bfc  = (const float*)d_in[11];
  unsigned char* ws = (unsigned char*)d_ws;

  // items: 3*262144 + 79872 + 262144 + 1024 + 262144 + 256 = 1,391,872 = 5437*256
  prep<<<5437, 256, 0, stream>>>(x, E, Wih0, Whh0, bih0, bhh0, Wih1, Whh1, bih1, bhh1, ws);
  lstm_sync<<<GB*GH, 256, 0, stream>>>(ws);
  fc_kernel<<<BATCH, 128, 0, stream>>>(ws, Wfc, bfc, (float*)d_out);
}

// Round 7
// 4384.008 us; speedup vs baseline: 4.8145x; 2.1038x over previous
//
#include <hip/hip_runtime.h>
#include <hip/hip_bf16.h>

#define VOCAB 78
#define EMBED 8
#define HID 256
#define BATCH 512
#define SEQ 512
#define G4H 1024

#define GB 8    // batch groups (16 WGs each sync together)
#define GH 16   // hidden groups -> 128 WGs, 1 per CU (LDS-bound)
#define BS 64   // batch rows per WG
#define HS 16   // hidden cols per WG

typedef short bf16x8 __attribute__((ext_vector_type(8)));
typedef float f32x4 __attribute__((ext_vector_type(4)));
typedef unsigned long long u64;

// ---- workspace layout (bytes) ----
#define OFF_WHH0 0                         // 512KB bf16 [1024][256]
#define OFF_WIH1 (512*1024)
#define OFF_WHH1 (1024*1024)
#define OFF_XG0  (1536*1024)               // 78*1024*4
#define OFF_B1   (OFF_XG0 + 320*1024)
#define OFF_XT   (OFF_B1 + 4096)           // int [512][512]
#define OFF_H0   (OFF_XT + 1024*1024)      // 2 x [512][256] bf16
#define OFF_H1   (OFF_H0 + 512*1024)
#define OFF_H1F  (OFF_H1 + 512*1024)       // [512][256] f32
#define OFF_CNT  (OFF_H1F + 512*1024)      // counters: 8 groups x 64B (cA,cB in one u64)
#define WS_NEED  (OFF_CNT + 1024)

__device__ __forceinline__ float sigm(float x){ return 1.f/(1.f + __expf(-x)); }
__device__ __forceinline__ float tanh_f(float x){
  float e = __expf(-2.f * fabsf(x));
  float r = (1.f - e) / (1.f + e);
  return copysignf(r, x);
}
__device__ __forceinline__ unsigned short f2b(float x){
  unsigned u = __float_as_uint(x);
  unsigned r = (u + 0x7FFFu + ((u >> 16) & 1u)) >> 16;
  return (unsigned short)r;
}

// ---------------- prep: bf16 weights, xg0 token table, x transpose, bias1, zero h/counters
__global__ void prep(const int* __restrict__ x, const float* __restrict__ E,
                     const float* __restrict__ Wih0, const float* __restrict__ Whh0,
                     const float* __restrict__ bih0, const float* __restrict__ bhh0,
                     const float* __restrict__ Wih1, const float* __restrict__ Whh1,
                     const float* __restrict__ bih1, const float* __restrict__ bhh1,
                     unsigned char* __restrict__ ws)
{
  unsigned short* Whh0b = (unsigned short*)(ws + OFF_WHH0);
  unsigned short* Wih1b = (unsigned short*)(ws + OFF_WIH1);
  unsigned short* Whh1b = (unsigned short*)(ws + OFF_WHH1);
  float* xg0 = (float*)(ws + OFF_XG0);
  float* b1  = (float*)(ws + OFF_B1);
  int*   xT  = (int*)(ws + OFF_XT);

  long id = (long)blockIdx.x * 256 + threadIdx.x;
  const long NW = 1024L * 256;
  if (id < NW) { Whh0b[id] = f2b(Whh0[id]); return; }
  id -= NW;
  if (id < NW) { Wih1b[id] = f2b(Wih1[id]); return; }
  id -= NW;
  if (id < NW) { Whh1b[id] = f2b(Whh1[id]); return; }
  id -= NW;
  if (id < (long)VOCAB*G4H) {
    int v = (int)(id / G4H), row = (int)(id % G4H);
    float s = bih0[row] + bhh0[row];
    if (v != 0) {
      #pragma unroll
      for (int e = 0; e < EMBED; e++) s += E[v*EMBED + e] * Wih0[row*EMBED + e];
    }
    xg0[id] = s; return;
  }
  id -= (long)VOCAB*G4H;
  if (id < (long)SEQ*BATCH) {
    int t = (int)(id / BATCH), b = (int)(id % BATCH);
    xT[t*BATCH + b] = x[b*SEQ + t]; return;
  }
  id -= (long)SEQ*BATCH;
  if (id < G4H) { b1[id] = bih1[id] + bhh1[id]; return; }
  id -= G4H;
  if (id < 262144) { ((unsigned*)(ws + OFF_H0))[id] = 0u; return; }
  id -= 262144;
  if (id < 256) { ((unsigned*)(ws + OFF_CNT))[id] = 0u; }
}

// ---------------- weight-stationary, skewed single-barrier LSTM
// h-store: agent atomic EXCHANGE (RMW at coherence point; return tracked by vmcnt ->
//   drained by __syncthreads before tid0 signals).
// h-load: SYSTEM-scope relaxed atomic load (bypass L1/L2 -> reads coherence point).
// R6 bug was NOT the protocol: the u64 fragment loads used stride kt*4 u64 (32B)
// instead of kt*8 (64B) -> read first 128 hidden elems twice, never the last 128.
__global__ __launch_bounds__(256, 1) void lstm_sync(unsigned char* __restrict__ ws)
{
  const unsigned short* Wg = (const unsigned short*)(ws + OFF_WHH0);
  const float* xg0 = (const float*)(ws + OFF_XG0);
  const float* b1  = (const float*)(ws + OFF_B1);
  const int*   xT  = (const int*)(ws + OFF_XT);
  unsigned short* h0g = (unsigned short*)(ws + OFF_H0);  // [2][512][256]
  unsigned short* h1g = (unsigned short*)(ws + OFF_H1);
  float* h1f = (float*)(ws + OFF_H1F);

  __shared__ __align__(16) unsigned char smem[3*32768 + 64*48];
  unsigned char* wlds = smem;
  unsigned char* hb   = smem + 3*32768;   // [64][48B] bounce for packed stores

  const int tid = threadIdx.x;
  const int m = tid >> 6, l = tid & 63, lc = l & 15, lq = l >> 4;
  const int gb = blockIdx.x & 7, gh = blockIdx.x >> 3;
  const int B0 = gb * BS, J = gh * HS;
  const int brow0 = B0 + m*16;

  unsigned* cA = (unsigned*)(ws + OFF_CNT) + gb*16;  // 64B per group line
  unsigned* cB = cA + 1;

  // --- stage weight slices into LDS (once), XOR-swizzled
  for (int idx = tid; idx < 3*64*32; idx += 256) {
    int mat = idx >> 11;
    int rem = idx & 2047;
    int cw  = rem >> 5;
    int c16 = rem & 31;
    int g = cw >> 4, r16 = cw & 15;
    int grow = g*256 + J + r16;
    bf16x8 v = *(const bf16x8*)(Wg + (size_t)mat*262144 + (size_t)grow*256 + c16*8);
    *(bf16x8*)(wlds + mat*32768 + cw*512 + ((c16*16) ^ ((cw&7)<<4))) = v;
  }

  float bias1v[4];
  #pragma unroll
  for (int g = 0; g < 4; g++) bias1v[g] = b1[g*256 + J + lc];

  int wb[3][4];
  const int swz = (lc & 7) << 4;
  #pragma unroll
  for (int g = 0; g < 4; g++) {
    int cw = g*16 + lc;
    wb[0][g] = 0*32768 + cw*512;
    wb[1][g] = 1*32768 + cw*512;
    wb[2][g] = 2*32768 + cw*512;
  }
  __syncthreads();

  float c0[4] = {0,0,0,0}, c1[4] = {0,0,0,0};
  u64 xret = 0;  // accumulated exchange returns (kept live; forces returning swaps)

#define MM(acc, a, mat)                                                          \
  _Pragma("unroll") for (int kt = 0; kt < 8; kt++) {                             \
    _Pragma("unroll") for (int g = 0; g < 4; g++) {                              \
      bf16x8 bfr = *(const bf16x8*)(wlds + wb[mat][g] + ((kt*64 + lq*16) ^ swz));\
      acc[g] = __builtin_amdgcn_mfma_f32_16x16x32_bf16(a[kt], bfr, acc[g], 0,0,0);\
    } }

  #pragma unroll 1
  for (int k = 0; k <= SEQ; ++k) {
    const int pk = k & 1, pkm1 = pk ^ 1;

    // ---- PIN: nothing below may move above the previous iteration's wait
    __builtin_amdgcn_sched_barrier(0);
    asm volatile("" ::: "memory");

    // ---- coherent (L1/L2-bypassing) h loads for this iteration
    // fragment kt covers hidden elems [kt*32, kt*32+32) => 64B = 8 u64 stride
    bf16x8 a0[8];  // h0(k-1) rows brow0+lc  (feeds BOTH L0(k) and L1(k-1))
    { const u64* hp = (const u64*)(h0g + (size_t)pkm1*131072 + (size_t)(brow0+lc)*256 + lq*8);
      #pragma unroll
      for (int kt = 0; kt < 8; kt++) {
        union { u64 q[2]; bf16x8 v; } u;
        u.q[0] = __hip_atomic_load(hp + kt*8 + 0, __ATOMIC_RELAXED, __HIP_MEMORY_SCOPE_SYSTEM);
        u.q[1] = __hip_atomic_load(hp + kt*8 + 1, __ATOMIC_RELAXED, __HIP_MEMORY_SCOPE_SYSTEM);
        a0[kt] = u.v;
      } }
    bf16x8 a1[8];  // h1(k-2)
    if (k >= 1) {
      const u64* hp = (const u64*)(h1g + (size_t)pk*131072 + (size_t)(brow0+lc)*256 + lq*8);
      #pragma unroll
      for (int kt = 0; kt < 8; kt++) {
        union { u64 q[2]; bf16x8 v; } u;
        u.q[0] = __hip_atomic_load(hp + kt*8 + 0, __ATOMIC_RELAXED, __HIP_MEMORY_SCOPE_SYSTEM);
        u.q[1] = __hip_atomic_load(hp + kt*8 + 1, __ATOMIC_RELAXED, __HIP_MEMORY_SCOPE_SYSTEM);
        a1[kt] = u.v;
      }
    }

    // ---- L0(k): h0(k) = lstm(h0(k-1), x(k))
    if (k < SEQ) {
      float xg[4][4];
      #pragma unroll
      for (int r = 0; r < 4; r++) {
        int tok = xT[k*BATCH + brow0 + lq*4 + r];          // plain: stays L1/L2 cached
        const float* tr = xg0 + (size_t)tok*G4H + J + lc;
        #pragma unroll
        for (int g = 0; g < 4; g++) xg[g][r] = tr[g*256];
      }
      f32x4 acc0[4] = {{0,0,0,0},{0,0,0,0},{0,0,0,0},{0,0,0,0}};
      MM(acc0, a0, 0);
      #pragma unroll
      for (int r = 0; r < 4; r++) {
        float gi = sigm (acc0[0][r] + xg[0][r]);
        float gf = sigm (acc0[1][r] + xg[1][r]);
        float gg = tanh_f(acc0[2][r] + xg[2][r]);
        float go = sigm (acc0[3][r] + xg[3][r]);
        float c = gf*c0[r] + gi*gg;  c0[r] = c;
        *(unsigned short*)(hb + (m*16 + lq*4 + r)*48 + lc*2) = f2b(go * tanh_f(c));
      }
      __syncthreads();
      { u64 pv = *(const u64*)(hb + (tid>>2)*48 + (tid&3)*8);
        u64* dp = (u64*)(h0g + (size_t)pk*131072 + (size_t)(B0 + (tid>>2))*256 + J + (tid&3)*4);
        xret ^= __hip_atomic_exchange(dp, pv, __ATOMIC_RELAXED, __HIP_MEMORY_SCOPE_AGENT); }
      // ---- PIN: exchanges may not sink below the barrier/signal
      asm volatile("" ::: "memory");
      __builtin_amdgcn_sched_barrier(0);
      __syncthreads();  // per-wave vmcnt(0): all swap RETURNS received -> data at L3
      if (tid == 0)
        __hip_atomic_fetch_add(cA, 1u, __ATOMIC_RELAXED, __HIP_MEMORY_SCOPE_AGENT);
    }

    // ---- L1(k-1): h1(k-1) = lstm(h0(k-1), h1(k-2))   [reuses a0]
    if (k >= 1) {
      f32x4 acc2[4];
      #pragma unroll
      for (int g = 0; g < 4; g++) { f32x4 v = {bias1v[g],bias1v[g],bias1v[g],bias1v[g]}; acc2[g] = v; }
      MM(acc2, a0, 1);
      MM(acc2, a1, 2);
      #pragma unroll
      for (int r = 0; r < 4; r++) {
        float gi = sigm (acc2[0][r]);
        float gf = sigm (acc2[1][r]);
        float gg = tanh_f(acc2[2][r]);
        float go = sigm (acc2[3][r]);
        float c = gf*c1[r] + gi*gg;  c1[r] = c;
        float h = go * tanh_f(c);
        *(unsigned short*)(hb + (m*16 + lq*4 + r)*48 + lc*2) = f2b(h);
        if (k == SEQ) h1f[(size_t)(brow0 + lq*4 + r)*256 + J + lc] = h;
      }
      __syncthreads();
      { u64 pv = *(const u64*)(hb + (tid>>2)*48 + (tid&3)*8);
        u64* dp = (u64*)(h1g + (size_t)pkm1*131072 + (size_t)(B0 + (tid>>2))*256 + J + (tid&3)*4);
        xret ^= __hip_atomic_exchange(dp, pv, __ATOMIC_RELAXED, __HIP_MEMORY_SCOPE_AGENT); }
      // ---- PIN: exchanges may not sink below the barrier/signal
      asm volatile("" ::: "memory");
      __builtin_amdgcn_sched_barrier(0);
      __syncthreads();
      if (tid == 0)
        __hip_atomic_fetch_add(cB, 1u, __ATOMIC_RELAXED, __HIP_MEMORY_SCOPE_AGENT);
    }

    // ---- ONE combined wait: A(k) and B(k-1)
    if (k < SEQ) {
      if (tid == 0) {
        unsigned needA = 16u * (unsigned)(k + 1);
        unsigned needB = 16u * (unsigned)k;
        while (1) {
          u64 cv = __hip_atomic_load((u64*)cA, __ATOMIC_RELAXED, __HIP_MEMORY_SCOPE_AGENT);
          if ((unsigned)cv >= needA && (unsigned)(cv >> 32) >= needB) break;
          __builtin_amdgcn_s_sleep(1);
        }
      }
      __syncthreads();
    }
  }
#undef MM
  asm volatile("" :: "v"(xret));  // keep exchange returns live (no DCE -> swaps return)
}

// ---------------- FC: out[512][78] = h1_last @ Wfc^T + bfc
__global__ void fc_kernel(const unsigned char* __restrict__ ws,
                          const float* __restrict__ Wfc, const float* __restrict__ bfc,
                          float* __restrict__ out)
{
  int b = blockIdx.x, v = threadIdx.x;
  if (v >= VOCAB) return;
  const float* h = (const float*)(ws + OFF_H1F) + (size_t)b*HID;
  const float* w = Wfc + (size_t)v*HID;
  float s = bfc[v];
  #pragma unroll 4
  for (int k = 0; k < HID; k += 4)
    s += h[k]*w[k] + h[k+1]*w[k+1] + h[k+2]*w[k+2] + h[k+3]*w[k+3];
  out[(size_t)b*VOCAB + v] = s;
}

extern "C" void kernel_launch(void* const* d_in, const int* in_sizes, int n_in,
                              void* d_out, int out_size, void* d_ws, size_t ws_size,
                              hipStream_t stream) {
  const int*   x    = (const int*)  d_in[0];
  const float* E    = (const float*)d_in[1];
  const float* Wih0 = (const float*)d_in[2];
  const float* Whh0 = (const float*)d_in[3];
  const float* bih0 = (const float*)d_in[4];
  const float* bhh0 = (const float*)d_in[5];
  const float* Wih1 = (const float*)d_in[6];
  const float* Whh1 = (const float*)d_in[7];
  const float* bih1 = (const float*)d_in[8];
  const float* bhh1 = (const float*)d_in[9];
  const float* Wfc  = (const float*)d_in[10];
  const float* bfc  = (const float*)d_in[11];
  unsigned char* ws = (unsigned char*)d_ws;

  prep<<<5437, 256, 0, stream>>>(x, E, Wih0, Whh0, bih0, bhh0, Wih1, Whh1, bih1, bhh1, ws);
  lstm_sync<<<GB*GH, 256, 0, stream>>>(ws);
  fc_kernel<<<BATCH, 128, 0, stream>>>(ws, Wfc, bfc, (float*)d_out);
}

// Round 8
// 4298.338 us; speedup vs baseline: 4.9105x; 1.0199x over previous
//
#include <hip/hip_runtime.h>
#include <hip/hip_bf16.h>

#define VOCAB 78
#define EMBED 8
#define HID 256
#define BATCH 512
#define SEQ 512
#define G4H 1024

#define GB 8    // batch groups (32 WGs each sync together)
#define GH 32   // hidden groups -> 256 WGs, 1 per CU
#define BS 64   // batch rows per WG
#define HS 8    // hidden cols per WG

typedef short bf16x8 __attribute__((ext_vector_type(8)));
typedef float f32x4 __attribute__((ext_vector_type(4)));
typedef unsigned long long u64;

// ---- workspace layout (bytes) ----
#define OFF_WHH0 0                         // 512KB bf16 [1024][256]
#define OFF_WIH1 (512*1024)
#define OFF_WHH1 (1024*1024)
#define OFF_XG0  (1536*1024)               // 78*1024*4
#define OFF_B1   (OFF_XG0 + 320*1024)
#define OFF_XT   (OFF_B1 + 4096)           // int [512][512]
#define OFF_H0   (OFF_XT + 1024*1024)      // 2 x [512][256] bf16
#define OFF_H1   (OFF_H0 + 512*1024)
#define OFF_H1F  (OFF_H1 + 512*1024)       // [512][256] f32
#define OFF_CNT  (OFF_H1F + 512*1024)      // 8 groups x 64B, single u32 each
#define WS_NEED  (OFF_CNT + 1024)

__device__ __forceinline__ float sigm(float x){ return 1.f/(1.f + __expf(-x)); }
__device__ __forceinline__ float tanh_f(float x){
  float e = __expf(-2.f * fabsf(x));
  float r = (1.f - e) / (1.f + e);
  return copysignf(r, x);
}
__device__ __forceinline__ unsigned short f2b(float x){
  unsigned u = __float_as_uint(x);
  unsigned r = (u + 0x7FFFu + ((u >> 16) & 1u)) >> 16;
  return (unsigned short)r;
}

// ---------------- prep: bf16 weights, xg0 token table, x transpose, bias1, zero h/counters
__global__ void prep(const int* __restrict__ x, const float* __restrict__ E,
                     const float* __restrict__ Wih0, const float* __restrict__ Whh0,
                     const float* __restrict__ bih0, const float* __restrict__ bhh0,
                     const float* __restrict__ Wih1, const float* __restrict__ Whh1,
                     const float* __restrict__ bih1, const float* __restrict__ bhh1,
                     unsigned char* __restrict__ ws)
{
  unsigned short* Whh0b = (unsigned short*)(ws + OFF_WHH0);
  unsigned short* Wih1b = (unsigned short*)(ws + OFF_WIH1);
  unsigned short* Whh1b = (unsigned short*)(ws + OFF_WHH1);
  float* xg0 = (float*)(ws + OFF_XG0);
  float* b1  = (float*)(ws + OFF_B1);
  int*   xT  = (int*)(ws + OFF_XT);

  long id = (long)blockIdx.x * 256 + threadIdx.x;
  const long NW = 1024L * 256;
  if (id < NW) { Whh0b[id] = f2b(Whh0[id]); return; }
  id -= NW;
  if (id < NW) { Wih1b[id] = f2b(Wih1[id]); return; }
  id -= NW;
  if (id < NW) { Whh1b[id] = f2b(Whh1[id]); return; }
  id -= NW;
  if (id < (long)VOCAB*G4H) {
    int v = (int)(id / G4H), row = (int)(id % G4H);
    float s = bih0[row] + bhh0[row];
    if (v != 0) {
      #pragma unroll
      for (int e = 0; e < EMBED; e++) s += E[v*EMBED + e] * Wih0[row*EMBED + e];
    }
    xg0[id] = s; return;
  }
  id -= (long)VOCAB*G4H;
  if (id < (long)SEQ*BATCH) {
    int t = (int)(id / BATCH), b = (int)(id % BATCH);
    xT[t*BATCH + b] = x[b*SEQ + t]; return;
  }
  id -= (long)SEQ*BATCH;
  if (id < G4H) { b1[id] = bih1[id] + bhh1[id]; return; }
  id -= G4H;
  if (id < 262144) { ((unsigned*)(ws + OFF_H0))[id] = 0u; return; }
  id -= 262144;
  if (id < 256) { ((unsigned*)(ws + OFF_CNT))[id] = 0u; }
}

// ---------------- weight-stationary LSTM, HS=8, merged-signal protocol
// 256 WGs: gb=bid&7 (batch group of 32 WGs), gh=bid>>3 (8-col hidden slice).
// Weights: 3 mats x 2 N-tiles x 16 rows x 256k in LDS (48KB). N-tile n packs
// gates {2n,2n+1} x 8 cols: lane lc holds gate 2n+(lc>>3), col J+(lc&7).
// Per step: L0(k) -> exchange h0 (drains under L1) ; L1(k-1) -> exchange h1 ;
// ONE barrier ; ONE fetch_add(+1) ; spin cnt>=32(k+1) guards {h0(k), h1(k-1)}.
__global__ __launch_bounds__(256, 1) void lstm_sync(unsigned char* __restrict__ ws)
{
  const unsigned short* Wg = (const unsigned short*)(ws + OFF_WHH0);
  const float* xg0 = (const float*)(ws + OFF_XG0);
  const float* b1  = (const float*)(ws + OFF_B1);
  const int*   xT  = (const int*)(ws + OFF_XT);
  unsigned short* h0g = (unsigned short*)(ws + OFF_H0);  // [2][512][256]
  unsigned short* h1g = (unsigned short*)(ws + OFF_H1);
  float* h1f = (float*)(ws + OFF_H1F);

  __shared__ __align__(16) unsigned char smem[49152 + 1024];
  unsigned char* wlds = smem;
  unsigned char* hb   = smem + 49152;     // [4 waves][16 rows][8 cols] u16

  const int tid = threadIdx.x;
  const int m = tid >> 6, l = tid & 63, lc = l & 15, lq = l >> 4;
  const int gb = blockIdx.x & 7, gh = blockIdx.x >> 3;
  const int B0 = gb * BS, J = gh * HS;
  const int brow0 = B0 + m*16;

  unsigned* cnt = (unsigned*)(ws + OFF_CNT) + gb*16;  // 64B-separated group counter

  // --- stage weight slices into LDS (once), XOR-swizzled. cw = n*16+i.
  for (int idx = tid; idx < 3*2*16*32; idx += 256) {
    int mat = idx >> 10;
    int rem = idx & 1023;
    int cw  = rem >> 5;          // 0..31
    int c16 = rem & 31;          // k-chunk of 8 bf16
    int n = cw >> 4, i = cw & 15;
    int grow = (2*n + (i>>3))*256 + J + (i&7);
    bf16x8 v = *(const bf16x8*)(Wg + (size_t)mat*262144 + (size_t)grow*256 + c16*8);
    *(bf16x8*)(wlds + mat*16384 + cw*512 + ((c16*16) ^ ((i&7)<<4))) = v;
  }

  // bias in MFMA layout (col index i=lc): gate 2n+(lc>>3), col J+(lc&7)
  float biasv[2];
  #pragma unroll
  for (int n = 0; n < 2; n++) biasv[n] = b1[(2*n + (lc>>3))*256 + J + (lc&7)];

  int wb[3][2];
  const int swz = (lc & 7) << 4;
  #pragma unroll
  for (int mat = 0; mat < 3; mat++)
    #pragma unroll
    for (int n = 0; n < 2; n++) wb[mat][n] = mat*16384 + (n*16 + lc)*512;
  __syncthreads();

  float c0[4] = {0,0,0,0}, c1[4] = {0,0,0,0};
  u64 xret = 0;

#define MM(acc, a, mat)                                                            \
  _Pragma("unroll") for (int kt = 0; kt < 8; kt++) {                               \
    _Pragma("unroll") for (int n = 0; n < 2; n++) {                                \
      bf16x8 bfr = *(const bf16x8*)(wlds + wb[mat][n] + ((kt*64 + lq*16) ^ swz));  \
      acc[n] = __builtin_amdgcn_mfma_f32_16x16x32_bf16(a[kt], bfr, acc[n], 0,0,0); \
    } }

  #pragma unroll 1
  for (int k = 0; k <= SEQ; ++k) {
    const int pk = k & 1, pkm1 = pk ^ 1;

    // ---- PIN: nothing below moves above the previous wait
    __builtin_amdgcn_sched_barrier(0);
    asm volatile("" ::: "memory");

    // ---- coherent h loads (L1/L2-bypassing); frag kt = 64B stride = 8 u64
    bf16x8 a0[8];  // h0(k-1), feeds L0(k) and L1(k-1)
    { const u64* hp = (const u64*)(h0g + (size_t)pkm1*131072 + (size_t)(brow0+lc)*256 + lq*8);
      #pragma unroll
      for (int kt = 0; kt < 8; kt++) {
        union { u64 q[2]; bf16x8 v; } u;
        u.q[0] = __hip_atomic_load(hp + kt*8 + 0, __ATOMIC_RELAXED, __HIP_MEMORY_SCOPE_SYSTEM);
        u.q[1] = __hip_atomic_load(hp + kt*8 + 1, __ATOMIC_RELAXED, __HIP_MEMORY_SCOPE_SYSTEM);
        a0[kt] = u.v;
      } }
    bf16x8 a1[8];  // h1(k-2)
    if (k >= 1) {
      const u64* hp = (const u64*)(h1g + (size_t)pk*131072 + (size_t)(brow0+lc)*256 + lq*8);
      #pragma unroll
      for (int kt = 0; kt < 8; kt++) {
        union { u64 q[2]; bf16x8 v; } u;
        u.q[0] = __hip_atomic_load(hp + kt*8 + 0, __ATOMIC_RELAXED, __HIP_MEMORY_SCOPE_SYSTEM);
        u.q[1] = __hip_atomic_load(hp + kt*8 + 1, __ATOMIC_RELAXED, __HIP_MEMORY_SCOPE_SYSTEM);
        a1[kt] = u.v;
      }
    }

    // ---- L0(k): h0(k) = lstm(h0(k-1), x(k))
    if (k < SEQ) {
      float xg[4][4];
      if (lc < 8) {
        #pragma unroll
        for (int r = 0; r < 4; r++) {
          int tok = xT[k*BATCH + brow0 + lq*4 + r];        // plain: L1/L2-cached
          const float* tr = xg0 + (size_t)tok*G4H + J + lc;
          #pragma unroll
          for (int g = 0; g < 4; g++) xg[g][r] = tr[g*256];
        }
      }
      f32x4 acc0[2] = {{0,0,0,0},{0,0,0,0}};
      MM(acc0, a0, 0);
      // cross-half gate partners (all lanes execute shuffles)
      float fpre[4], opre[4];
      #pragma unroll
      for (int r = 0; r < 4; r++) {
        fpre[r] = __shfl_xor(acc0[0][r], 8, 64);
        opre[r] = __shfl_xor(acc0[1][r], 8, 64);
      }
      if (lc < 8) {
        #pragma unroll
        for (int r = 0; r < 4; r++) {
          float gi = sigm (acc0[0][r] + xg[0][r]);
          float gf = sigm (fpre[r]    + xg[1][r]);
          float gg = tanh_f(acc0[1][r] + xg[2][r]);
          float go = sigm (opre[r]    + xg[3][r]);
          float c = gf*c0[r] + gi*gg;  c0[r] = c;
          *(unsigned short*)(hb + m*256 + (lq*4 + r)*16 + lc*2) = f2b(go * tanh_f(c));
        }
      }
      // wave-local pack + exchange issue (no barrier; lgkmcnt orders ds ops)
      if (l < 32) {
        int row = l >> 1, half = l & 1;
        u64 pv = *(const u64*)(hb + m*256 + row*16 + half*8);
        u64* dp = (u64*)(h0g + (size_t)pk*131072 + (size_t)(B0 + m*16 + row)*256 + J + half*4);
        xret ^= __hip_atomic_exchange(dp, pv, __ATOMIC_RELAXED, __HIP_MEMORY_SCOPE_AGENT);
      }
      // PIN: exchanges issued here; drain hides under L1 compute
      asm volatile("" ::: "memory");
      __builtin_amdgcn_sched_barrier(0);
    }

    // ---- L1(k-1): h1(k-1) = lstm(h0(k-1), h1(k-2))   [reuses a0]
    if (k >= 1) {
      f32x4 acc2[2];
      #pragma unroll
      for (int n = 0; n < 2; n++) { f32x4 v = {biasv[n],biasv[n],biasv[n],biasv[n]}; acc2[n] = v; }
      MM(acc2, a0, 1);
      MM(acc2, a1, 2);
      float fpre[4], opre[4];
      #pragma unroll
      for (int r = 0; r < 4; r++) {
        fpre[r] = __shfl_xor(acc2[0][r], 8, 64);
        opre[r] = __shfl_xor(acc2[1][r], 8, 64);
      }
      if (lc < 8) {
        #pragma unroll
        for (int r = 0; r < 4; r++) {
          float gi = sigm (acc2[0][r]);
          float gf = sigm (fpre[r]);
          float gg = tanh_f(acc2[1][r]);
          float go = sigm (opre[r]);
          float c = gf*c1[r] + gi*gg;  c1[r] = c;
          float h = go * tanh_f(c);
          *(unsigned short*)(hb + m*256 + (lq*4 + r)*16 + lc*2) = f2b(h);
          if (k == SEQ) h1f[(size_t)(brow0 + lq*4 + r)*256 + J + lc] = h;
        }
      }
      if (l < 32) {
        int row = l >> 1, half = l & 1;
        u64 pv = *(const u64*)(hb + m*256 + row*16 + half*8);
        u64* dp = (u64*)(h1g + (size_t)pkm1*131072 + (size_t)(B0 + m*16 + row)*256 + J + half*4);
        xret ^= __hip_atomic_exchange(dp, pv, __ATOMIC_RELAXED, __HIP_MEMORY_SCOPE_AGENT);
      }
      asm volatile("" ::: "memory");
      __builtin_amdgcn_sched_barrier(0);
    }

    // ---- ONE drain barrier + ONE merged signal + wait
    __syncthreads();   // per-wave vmcnt(0): all exchange returns in -> data at L3
    if (tid == 0)
      __hip_atomic_fetch_add(cnt, 1u, __ATOMIC_RELAXED, __HIP_MEMORY_SCOPE_AGENT);
    if (k < SEQ) {
      if (tid == 0) {
        unsigned need = 32u * (unsigned)(k + 1);
        while (__hip_atomic_load(cnt, __ATOMIC_RELAXED, __HIP_MEMORY_SCOPE_AGENT) < need)
          __builtin_amdgcn_s_sleep(1);
      }
      __syncthreads();
    }
  }
#undef MM
  asm volatile("" :: "v"(xret));  // keep exchange returns live
}

// ---------------- FC: out[512][78] = h1_last @ Wfc^T + bfc
__global__ void fc_kernel(const unsigned char* __restrict__ ws,
                          const float* __restrict__ Wfc, const float* __restrict__ bfc,
                          float* __restrict__ out)
{
  int b = blockIdx.x, v = threadIdx.x;
  if (v >= VOCAB) return;
  const float* h = (const float*)(ws + OFF_H1F) + (size_t)b*HID;
  const float* w = Wfc + (size_t)v*HID;
  float s = bfc[v];
  #pragma unroll 4
  for (int k = 0; k < HID; k += 4)
    s += h[k]*w[k] + h[k+1]*w[k+1] + h[k+2]*w[k+2] + h[k+3]*w[k+3];
  out[(size_t)b*VOCAB + v] = s;
}

extern "C" void kernel_launch(void* const* d_in, const int* in_sizes, int n_in,
                              void* d_out, int out_size, void* d_ws, size_t ws_size,
                              hipStream_t stream) {
  const int*   x    = (const int*)  d_in[0];
  const float* E    = (const float*)d_in[1];
  const float* Wih0 = (const float*)d_in[2];
  const float* Whh0 = (const float*)d_in[3];
  const float* bih0 = (const float*)d_in[4];
  const float* bhh0 = (const float*)d_in[5];
  const float* Wih1 = (const float*)d_in[6];
  const float* Whh1 = (const float*)d_in[7];
  const float* bih1 = (const float*)d_in[8];
  const float* bhh1 = (const float*)d_in[9];
  const float* Wfc  = (const float*)d_in[10];
  const float* bfc  = (const float*)d_in[11];
  unsigned char* ws = (unsigned char*)d_ws;

  prep<<<5437, 256, 0, stream>>>(x, E, Wih0, Whh0, bih0, bhh0, Wih1, Whh1, bih1, bhh1, ws);
  lstm_sync<<<GB*GH, 256, 0, stream>>>(ws);
  fc_kernel<<<BATCH, 128, 0, stream>>>(ws, Wfc, bfc, (float*)d_out);
}